// Round 1
// baseline (1125.759 us; speedup 1.0000x reference)
//
#include <hip/hip_runtime.h>
#include <stdint.h>

#define LEVELS 16
#define FEAT 2
#define TABLE_SIZE 524288
#define TMASK (TABLE_SIZE - 1)

typedef float f32x2 __attribute__((ext_vector_type(2)));
typedef float f32x4 __attribute__((ext_vector_type(4)));
typedef float f32x4u __attribute__((ext_vector_type(4), aligned(8)));  // 16B load, 8B-aligned ok

__device__ __constant__ int kRes[LEVELS] = {
    16, 22, 30, 42, 58, 80, 111, 153, 212, 294, 406, 561, 775, 1072, 1481, 2047
};

#define P1 73856093u
#define P2 19349663u
#define P3 83492791u

// Levels 0-4 dense in global scratch (levels 0-1 tables are tiny: 38KB/95KB).
#define D0 17
#define N0 4913
#define D1 23
#define N1 12167
#define D2 31
#define N2 29791
#define D3 43
#define N3 79507
#define D4 59
#define N4 205379
#define NDENSE (N0 + N1 + N2 + N3 + N4)

// ---------------- one-time remap: hashed tables 0-4 -> dense [D^3] layout ----------------
__global__ __launch_bounds__(256) void remap_kernel(
    const float* __restrict__ tables,
    f32x2* __restrict__ dense)   // [NDENSE]
{
    const int d = blockIdx.x * 256 + threadIdx.x;
    if (d >= NDENSE) return;
    int l, D, rel;
    if (d < N0)                          { l = 0; D = D0; rel = d; }
    else if (d < N0 + N1)                { l = 1; D = D1; rel = d - N0; }
    else if (d < N0 + N1 + N2)           { l = 2; D = D2; rel = d - N0 - N1; }
    else if (d < N0 + N1 + N2 + N3)      { l = 3; D = D3; rel = d - N0 - N1 - N2; }
    else                                 { l = 4; D = D4; rel = d - N0 - N1 - N2 - N3; }
    const uint32_t bx = rel / (D * D);
    const uint32_t r  = rel - bx * (D * D);
    const uint32_t by = r / D;
    const uint32_t bz = r - by * D;
    const uint32_t slot = ((bx * P1) ^ (by * P2) ^ (bz * P3)) & TMASK;
    const f32x2* __restrict__ tab = reinterpret_cast<const f32x2*>(tables) + (size_t)l * TABLE_SIZE;
    dense[d] = tab[slot];
}

// ---------------- levels 0-4 from dense global tables: 4 pts/thread, 16x16B gathers in flight ----------------
__device__ __constant__ int   kDD[5]    = { D0, D1, D2, D3, D4 };
__device__ __constant__ int   kDOff[5]  = { 0, N0, N0 + N1, N0 + N1 + N2, N0 + N1 + N2 + N3 };
__device__ __constant__ float kDRes[5]  = { 16.0f, 22.0f, 30.0f, 42.0f, 58.0f };

__global__ __launch_bounds__(256) void encode_dense_kernel(
    const float* __restrict__ x,
    const f32x2* __restrict__ dense,
    f32x2* __restrict__ ws,
    int n, int nb)
{
    const int lsel = blockIdx.x / nb;
    const int blk  = blockIdx.x - lsel * nb;
    const int t    = threadIdx.x;
    const int p0   = blk * 1024;

    __shared__ float sx[1024 * 3];
    const long long total3 = (long long)n * 3;
    const long long gbase  = (long long)p0 * 3;
#pragma unroll
    for (int k = 0; k < 12; ++k) {
        long long g = gbase + k * 256 + t;
        sx[k * 256 + t] = (g < total3) ? __builtin_nontemporal_load(x + g) : 0.0f;
    }
    __syncthreads();

    const int   D    = kDD[lsel];
    const int   DD   = D * D;
    const float resf = kDRes[lsel];
    const f32x2* __restrict__ tabd = dense + kDOff[lsel];

    int   base[4];
    float wxa[4], wya[4], wza[4];
#pragma unroll
    for (int s = 0; s < 4; ++s) {
        const int tp = s * 256 + t;
        const float fx = sx[3 * tp + 0] * resf;
        const float fy = sx[3 * tp + 1] * resf;
        const float fz = sx[3 * tp + 2] * resf;
        const float flx = floorf(fx), fly = floorf(fy), flz = floorf(fz);
        wxa[s] = fx - flx; wya[s] = fy - fly; wza[s] = fz - flz;
        base[s] = ((int)flx * D + (int)fly) * D + (int)flz;
    }

    // 16 pair-loads (16B each), all in flight before any use.
    f32x4u v[4][4];
#pragma unroll
    for (int s = 0; s < 4; ++s)
#pragma unroll
        for (int p = 0; p < 4; ++p) {
            const int off = ((p & 2) ? DD : 0) + ((p & 1) ? D : 0);
            v[s][p] = *reinterpret_cast<const f32x4u*>(tabd + base[s] + off);
        }
    __builtin_amdgcn_sched_barrier(0);

#pragma unroll
    for (int s = 0; s < 4; ++s) {
        const float wx = wxa[s], wy = wya[s], wz = wza[s];
        const float ux = 1.0f - wx, uy = 1.0f - wy, uz = 1.0f - wz;
        float f0 = 0.0f, f1 = 0.0f;
#pragma unroll
        for (int p = 0; p < 4; ++p) {
            const float wxy = ((p & 2) ? wx : ux) * ((p & 1) ? wy : uy);
            f0 = fmaf(wxy, fmaf(uz, v[s][p].x, wz * v[s][p].z), f0);
            f1 = fmaf(wxy, fmaf(uz, v[s][p].y, wz * v[s][p].w), f1);
        }
        const int i = p0 + s * 256 + t;
        if (i < n) {
            f32x2 r; r.x = f0; r.y = f1;
            __builtin_nontemporal_store(r, ws + (size_t)lsel * n + i);
        }
    }
}

// ---------------- levels 5-15: hashed gathers, 4 pts/thread, 32 gathers in flight ----------------
__global__ __launch_bounds__(256) void encode_level_kernel(
    const float* __restrict__ x,
    const float* __restrict__ tables,
    f32x2* __restrict__ ws,
    int n, int nb)
{
    const int l   = 5 + blockIdx.x / nb;
    const int blk = blockIdx.x - (l - 5) * nb;
    const int t   = threadIdx.x;
    const int p0  = blk * 1024;

    __shared__ float sx[1024 * 3];
    const long long total3 = (long long)n * 3;
    const long long gbase  = (long long)p0 * 3;
#pragma unroll
    for (int k = 0; k < 12; ++k) {
        long long g = gbase + k * 256 + t;
        sx[k * 256 + t] = (g < total3) ? __builtin_nontemporal_load(x + g) : 0.0f;
    }
    __syncthreads();

    const float resf = (float)kRes[l];
    const f32x2* __restrict__ tab = reinterpret_cast<const f32x2*>(tables) + (size_t)l * TABLE_SIZE;

    uint32_t idx[4][8];
    float    wxa[4], wya[4], wza[4];
#pragma unroll
    for (int s = 0; s < 4; ++s) {
        const int tp = s * 256 + t;
        const float fx = sx[3 * tp + 0] * resf;
        const float fy = sx[3 * tp + 1] * resf;
        const float fz = sx[3 * tp + 2] * resf;
        const float flx = floorf(fx), fly = floorf(fy), flz = floorf(fz);
        wxa[s] = fx - flx; wya[s] = fy - fly; wza[s] = fz - flz;
        const uint32_t hx0 = (uint32_t)(int)flx * P1, hx1 = hx0 + P1;
        const uint32_t hy0 = (uint32_t)(int)fly * P2, hy1 = hy0 + P2;
        const uint32_t hz0 = (uint32_t)(int)flz * P3, hz1 = hz0 + P3;
#pragma unroll
        for (int c = 0; c < 8; ++c) {
            const uint32_t hx = (c & 4) ? hx1 : hx0;
            const uint32_t hy = (c & 2) ? hy1 : hy0;
            const uint32_t hz = (c & 1) ? hz1 : hz0;
            idx[s][c] = (hx ^ hy ^ hz) & TMASK;
        }
    }

    // 32 gathers, all in flight before any FMA (sched_barrier pins the clause).
    f32x2 v[4][8];
#pragma unroll
    for (int s = 0; s < 4; ++s)
#pragma unroll
        for (int c = 0; c < 8; ++c)
            v[s][c] = tab[idx[s][c]];
    __builtin_amdgcn_sched_barrier(0);

#pragma unroll
    for (int s = 0; s < 4; ++s) {
        const float wx = wxa[s], wy = wya[s], wz = wza[s];
        const float ux = 1.0f - wx, uy = 1.0f - wy, uz = 1.0f - wz;
        float f0 = 0.0f, f1 = 0.0f;
#pragma unroll
        for (int c = 0; c < 8; ++c) {
            const float w = ((c & 4) ? wx : ux) * ((c & 2) ? wy : uy) * ((c & 1) ? wz : uz);
            f0 = fmaf(w, v[s][c].x, f0);
            f1 = fmaf(w, v[s][c].y, f1);
        }
        const int i = p0 + s * 256 + t;
        if (i < n) {
            f32x2 r; r.x = f0; r.y = f1;
            __builtin_nontemporal_store(r, ws + (size_t)l * n + i);
        }
    }
}

// ---------------- transpose [LEVELS][n][2] -> [n][32], LDS-tiled ----------------
__global__ __launch_bounds__(256) void transpose_kernel(
    const f32x2* __restrict__ ws,
    float* __restrict__ out,
    int n)
{
    __shared__ float s[256 * 33];
    const int t  = threadIdx.x;
    const int p0 = blockIdx.x * 256;
    const int m  = min(256, n - p0);

    if (t < m) {
#pragma unroll
        for (int l = 0; l < LEVELS; ++l) {
            const f32x2 e = __builtin_nontemporal_load(ws + (size_t)l * n + p0 + t);
            s[t * 33 + 2 * l + 0] = e.x;
            s[t * 33 + 2 * l + 1] = e.y;
        }
    }
    __syncthreads();

    const int nchunk = m * 8;
    f32x4* __restrict__ o4 = reinterpret_cast<f32x4*>(out) + (size_t)p0 * 8;
#pragma unroll
    for (int j = 0; j < 8; ++j) {
        const int cl = j * 256 + t;
        if (cl < nchunk) {
            const int p = cl >> 3, ch = cl & 7;
            f32x4 q;
            q.x = s[p * 33 + ch * 4 + 0];
            q.y = s[p * 33 + ch * 4 + 1];
            q.z = s[p * 33 + ch * 4 + 2];
            q.w = s[p * 33 + ch * 4 + 3];
            __builtin_nontemporal_store(q, o4 + cl);
        }
    }
}

// ---------------- fallback: fused single-kernel path (if ws too small) ----------------
__global__ __launch_bounds__(256) void hashgrid_enc_kernel(
    const float* __restrict__ x,
    const float* __restrict__ tables,
    float* __restrict__ out,
    int n)
{
    __shared__ float sx[256 * 3];
    const int t = threadIdx.x;
    const int block0 = blockIdx.x * 256;
    const long long total3 = (long long)n * 3;
    const long long gbase = (long long)block0 * 3;
#pragma unroll
    for (int k = 0; k < 3; ++k) {
        long long g = gbase + k * 256 + t;
        sx[k * 256 + t] = (g < total3) ? x[g] : 0.0f;
    }
    __syncthreads();
    const int i = block0 + t;
    if (i >= n) return;
    const float px = sx[3 * t + 0];
    const float py = sx[3 * t + 1];
    const float pz = sx[3 * t + 2];
    float outv[2 * LEVELS];
#pragma unroll
    for (int l = 0; l < LEVELS; ++l) {
        const float resf = (float)kRes[l];
        const float fx = px * resf, fy = py * resf, fz = pz * resf;
        const float flx = floorf(fx), fly = floorf(fy), flz = floorf(fz);
        const float wx = fx - flx, wy = fy - fly, wz = fz - flz;
        const float ux = 1.0f - wx, uy = 1.0f - wy, uz = 1.0f - wz;
        const uint32_t hx0 = (uint32_t)(int)flx * P1, hx1 = hx0 + P1;
        const uint32_t hy0 = (uint32_t)(int)fly * P2, hy1 = hy0 + P2;
        const uint32_t hz0 = (uint32_t)(int)flz * P3, hz1 = hz0 + P3;
        const float* __restrict__ tab = tables + (size_t)l * (TABLE_SIZE * FEAT);
        float f0 = 0.0f, f1 = 0.0f;
#pragma unroll
        for (int c = 0; c < 8; ++c) {
            const uint32_t hx = (c & 4) ? hx1 : hx0;
            const uint32_t hy = (c & 2) ? hy1 : hy0;
            const uint32_t hz = (c & 1) ? hz1 : hz0;
            const uint32_t idx = (hx ^ hy ^ hz) & TMASK;
            const float2 v = *reinterpret_cast<const float2*>(tab + (size_t)idx * FEAT);
            const float w = ((c & 4) ? wx : ux) * ((c & 2) ? wy : uy) * ((c & 1) ? wz : uz);
            f0 = fmaf(w, v.x, f0);
            f1 = fmaf(w, v.y, f1);
        }
        outv[2 * l + 0] = f0;
        outv[2 * l + 1] = f1;
    }
    float4* __restrict__ o4 = reinterpret_cast<float4*>(out + (size_t)i * (2 * LEVELS));
#pragma unroll
    for (int k = 0; k < 8; ++k) {
        o4[k] = make_float4(outv[4 * k + 0], outv[4 * k + 1],
                            outv[4 * k + 2], outv[4 * k + 3]);
    }
}

extern "C" void kernel_launch(void* const* d_in, const int* in_sizes, int n_in,
                              void* d_out, int out_size, void* d_ws, size_t ws_size,
                              hipStream_t stream) {
    const float* x = (const float*)d_in[0];
    const float* tables = (const float*)d_in[1];
    float* out = (float*)d_out;
    const int n = in_sizes[0] / 3;

    const size_t ws_elems  = (size_t)LEVELS * (size_t)n;          // f32x2 results
    const size_t ws_needed = (ws_elems + NDENSE + 2) * sizeof(f32x2);
    if (ws_size >= ws_needed) {
        f32x2* ws    = (f32x2*)d_ws;
        f32x2* dense = ws + ws_elems;

        hipLaunchKernelGGL(remap_kernel, dim3((NDENSE + 255) / 256), dim3(256), 0, stream,
                           tables, dense);

        const int nb1024 = (n + 1023) / 1024;
        hipLaunchKernelGGL(encode_dense_kernel, dim3(nb1024 * 5), dim3(256), 0, stream,
                           x, dense, ws, n, nb1024);
        hipLaunchKernelGGL(encode_level_kernel, dim3(nb1024 * 11), dim3(256), 0, stream,
                           x, tables, ws, n, nb1024);

        const int nb256 = (n + 255) / 256;
        hipLaunchKernelGGL(transpose_kernel, dim3(nb256), dim3(256), 0, stream,
                           ws, out, n);
    } else {
        const int nb = (n + 255) / 256;
        hipLaunchKernelGGL(hashgrid_enc_kernel, dim3(nb), dim3(256), 0, stream,
                           x, tables, out, n);
    }
}

// Round 2
// 1047.715 us; speedup vs baseline: 1.0745x; 1.0745x over previous
//
#include <hip/hip_runtime.h>
#include <stdint.h>

#define LEVELS 16
#define FEAT 2
#define TABLE_SIZE 524288
#define TMASK (TABLE_SIZE - 1)

typedef float f32x2 __attribute__((ext_vector_type(2)));
typedef float f32x4 __attribute__((ext_vector_type(4)));
typedef float f32x4u __attribute__((ext_vector_type(4), aligned(8)));  // 16B load, 8B-aligned ok

__device__ __constant__ int kRes[LEVELS] = {
    16, 22, 30, 42, 58, 80, 111, 153, 212, 294, 406, 561, 775, 1072, 1481, 2047
};

#define P1 73856093u
#define P2 19349663u
#define P3 83492791u

// Dense (collision-free replicated) tables for levels 0-5 in global scratch.
#define D0 17
#define N0 4913
#define D1 23
#define N1 12167
#define D2 31
#define N2 29791
#define D3 43
#define N3 79507
#define D4 59
#define N4 205379
#define D5 81
#define N5 531441
#define NDENSE5 (N0 + N1 + N2 + N3 + N4)              // plan B: levels 0-4 dense
#define NDENSE6 (NDENSE5 + N5)                        // plan A: levels 0-5 dense

__device__ __constant__ int   kDD[6]   = { D0, D1, D2, D3, D4, D5 };
__device__ __constant__ int   kDOff[6] = { 0, N0, N0+N1, N0+N1+N2, N0+N1+N2+N3, NDENSE5 };
__device__ __constant__ float kDRes[6] = { 16.0f, 22.0f, 30.0f, 42.0f, 58.0f, 80.0f };
__device__ __constant__ int   kDCum[7] = { 0, N0, N0+N1, N0+N1+N2, N0+N1+N2+N3, NDENSE5, NDENSE6 };

// ---------------- one-time remap: hashed tables -> dense [D^3] layout ----------------
__global__ __launch_bounds__(256) void remap_kernel(
    const float* __restrict__ tables,
    f32x2* __restrict__ dense,
    int total)   // NDENSE5 or NDENSE6
{
    const int d = blockIdx.x * 256 + threadIdx.x;
    if (d >= total) return;
    int l = 0;
#pragma unroll
    for (int k = 1; k < 6; ++k)
        if (d >= kDCum[k]) l = k;
    const int D   = kDD[l];
    const int rel = d - kDCum[l];
    const uint32_t bx = rel / (D * D);
    const uint32_t r  = rel - bx * (D * D);
    const uint32_t by = r / D;
    const uint32_t bz = r - by * D;
    const uint32_t slot = ((bx * P1) ^ (by * P2) ^ (bz * P3)) & TMASK;
    const f32x2* __restrict__ tab = reinterpret_cast<const f32x2*>(tables) + (size_t)l * TABLE_SIZE;
    dense[d] = tab[slot];
}

// ---------------- dense levels: one pass over x, loop over ndlev levels ----------------
__global__ __launch_bounds__(256) void encode_dense_kernel(
    const float* __restrict__ x,
    const f32x2* __restrict__ dense,
    f32x2* __restrict__ ws,
    int n, int ndlev)
{
    const int blk = blockIdx.x;
    const int t   = threadIdx.x;
    const int p0  = blk * 512;

    __shared__ float sx[512 * 3];
    const long long total3 = (long long)n * 3;
    const long long gbase  = (long long)p0 * 3;
#pragma unroll
    for (int k = 0; k < 6; ++k) {
        long long g = gbase + k * 256 + t;
        sx[k * 256 + t] = (g < total3) ? __builtin_nontemporal_load(x + g) : 0.0f;
    }
    __syncthreads();

    const float px[2] = { sx[3 * t + 0],          sx[3 * (t + 256) + 0] };
    const float py[2] = { sx[3 * t + 1],          sx[3 * (t + 256) + 1] };
    const float pz[2] = { sx[3 * t + 2],          sx[3 * (t + 256) + 2] };

    for (int l = 0; l < ndlev; ++l) {
        const int   D    = kDD[l];
        const int   DD   = D * D;
        const float resf = kDRes[l];
        const f32x2* __restrict__ tabd = dense + kDOff[l];

        int   base[2];
        float wxa[2], wya[2], wza[2];
#pragma unroll
        for (int s = 0; s < 2; ++s) {
            const float fx = px[s] * resf;
            const float fy = py[s] * resf;
            const float fz = pz[s] * resf;
            const float flx = floorf(fx), fly = floorf(fy), flz = floorf(fz);
            wxa[s] = fx - flx; wya[s] = fy - fly; wza[s] = fz - flz;
            base[s] = ((int)flx * D + (int)fly) * D + (int)flz;
        }

        // 8 pair-loads (16B each) in flight.
        f32x4u v[2][4];
#pragma unroll
        for (int s = 0; s < 2; ++s)
#pragma unroll
            for (int p = 0; p < 4; ++p) {
                const int off = ((p & 2) ? DD : 0) + ((p & 1) ? D : 0);
                v[s][p] = *reinterpret_cast<const f32x4u*>(tabd + base[s] + off);
            }

#pragma unroll
        for (int s = 0; s < 2; ++s) {
            const float wx = wxa[s], wy = wya[s], wz = wza[s];
            const float ux = 1.0f - wx, uy = 1.0f - wy, uz = 1.0f - wz;
            float f0 = 0.0f, f1 = 0.0f;
#pragma unroll
            for (int p = 0; p < 4; ++p) {
                const float wxy = ((p & 2) ? wx : ux) * ((p & 1) ? wy : uy);
                f0 = fmaf(wxy, fmaf(uz, v[s][p].x, wz * v[s][p].z), f0);
                f1 = fmaf(wxy, fmaf(uz, v[s][p].y, wz * v[s][p].w), f1);
            }
            const int i = p0 + s * 256 + t;
            if (i < n) {
                f32x2 r; r.x = f0; r.y = f1;
                __builtin_nontemporal_store(r, ws + (size_t)l * n + i);
            }
        }
    }
}

// ---------------- hashed levels l0..15: round-0 structure (2 pts/thread) ----------------
__global__ __launch_bounds__(256) void encode_level_kernel(
    const float* __restrict__ x,
    const float* __restrict__ tables,
    f32x2* __restrict__ ws,
    int n, int nb, int l0)
{
    const int l   = l0 + blockIdx.x / nb;
    const int blk = blockIdx.x - (l - l0) * nb;
    const int t   = threadIdx.x;
    const int p0  = blk * 512;

    __shared__ float sx[512 * 3];
    const long long total3 = (long long)n * 3;
    const long long gbase  = (long long)p0 * 3;
#pragma unroll
    for (int k = 0; k < 6; ++k) {
        long long g = gbase + k * 256 + t;
        sx[k * 256 + t] = (g < total3) ? __builtin_nontemporal_load(x + g) : 0.0f;
    }
    __syncthreads();

    const float resf = (float)kRes[l];
    const f32x2* __restrict__ tab = reinterpret_cast<const f32x2*>(tables) + (size_t)l * TABLE_SIZE;

    uint32_t idx[2][8];
    float    wgt[2][8];
#pragma unroll
    for (int s = 0; s < 2; ++s) {
        const int tp = s * 256 + t;
        const float fx = sx[3 * tp + 0] * resf;
        const float fy = sx[3 * tp + 1] * resf;
        const float fz = sx[3 * tp + 2] * resf;
        const float flx = floorf(fx), fly = floorf(fy), flz = floorf(fz);
        const float wx = fx - flx, wy = fy - fly, wz = fz - flz;
        const float ux = 1.0f - wx, uy = 1.0f - wy, uz = 1.0f - wz;
        const uint32_t hx0 = (uint32_t)(int)flx * P1, hx1 = hx0 + P1;
        const uint32_t hy0 = (uint32_t)(int)fly * P2, hy1 = hy0 + P2;
        const uint32_t hz0 = (uint32_t)(int)flz * P3, hz1 = hz0 + P3;
#pragma unroll
        for (int c = 0; c < 8; ++c) {
            const uint32_t hx = (c & 4) ? hx1 : hx0;
            const uint32_t hy = (c & 2) ? hy1 : hy0;
            const uint32_t hz = (c & 1) ? hz1 : hz0;
            idx[s][c] = (hx ^ hy ^ hz) & TMASK;
            wgt[s][c] = ((c & 4) ? wx : ux) * ((c & 2) ? wy : uy) * ((c & 1) ? wz : uz);
        }
    }

    f32x2 v[2][8];
#pragma unroll
    for (int s = 0; s < 2; ++s)
#pragma unroll
        for (int c = 0; c < 8; ++c)
            v[s][c] = tab[idx[s][c]];

#pragma unroll
    for (int s = 0; s < 2; ++s) {
        float f0 = 0.0f, f1 = 0.0f;
#pragma unroll
        for (int c = 0; c < 8; ++c) {
            f0 = fmaf(wgt[s][c], v[s][c].x, f0);
            f1 = fmaf(wgt[s][c], v[s][c].y, f1);
        }
        const int i = p0 + s * 256 + t;
        if (i < n) {
            f32x2 r; r.x = f0; r.y = f1;
            __builtin_nontemporal_store(r, ws + (size_t)l * n + i);
        }
    }
}

// ---------------- transpose [LEVELS][n][2] -> [n][32], LDS-tiled ----------------
__global__ __launch_bounds__(256) void transpose_kernel(
    const f32x2* __restrict__ ws,
    float* __restrict__ out,
    int n)
{
    __shared__ float s[256 * 33];
    const int t  = threadIdx.x;
    const int p0 = blockIdx.x * 256;
    const int m  = min(256, n - p0);

    if (t < m) {
#pragma unroll
        for (int l = 0; l < LEVELS; ++l) {
            const f32x2 e = __builtin_nontemporal_load(ws + (size_t)l * n + p0 + t);
            s[t * 33 + 2 * l + 0] = e.x;
            s[t * 33 + 2 * l + 1] = e.y;
        }
    }
    __syncthreads();

    const int nchunk = m * 8;
    f32x4* __restrict__ o4 = reinterpret_cast<f32x4*>(out) + (size_t)p0 * 8;
#pragma unroll
    for (int j = 0; j < 8; ++j) {
        const int cl = j * 256 + t;
        if (cl < nchunk) {
            const int p = cl >> 3, ch = cl & 7;
            f32x4 q;
            q.x = s[p * 33 + ch * 4 + 0];
            q.y = s[p * 33 + ch * 4 + 1];
            q.z = s[p * 33 + ch * 4 + 2];
            q.w = s[p * 33 + ch * 4 + 3];
            __builtin_nontemporal_store(q, o4 + cl);
        }
    }
}

// ---------------- fallback: fused single-kernel path (if ws too small) ----------------
__global__ __launch_bounds__(256) void hashgrid_enc_kernel(
    const float* __restrict__ x,
    const float* __restrict__ tables,
    float* __restrict__ out,
    int n)
{
    __shared__ float sx[256 * 3];
    const int t = threadIdx.x;
    const int block0 = blockIdx.x * 256;
    const long long total3 = (long long)n * 3;
    const long long gbase = (long long)block0 * 3;
#pragma unroll
    for (int k = 0; k < 3; ++k) {
        long long g = gbase + k * 256 + t;
        sx[k * 256 + t] = (g < total3) ? x[g] : 0.0f;
    }
    __syncthreads();
    const int i = block0 + t;
    if (i >= n) return;
    const float px = sx[3 * t + 0];
    const float py = sx[3 * t + 1];
    const float pz = sx[3 * t + 2];
    float outv[2 * LEVELS];
#pragma unroll
    for (int l = 0; l < LEVELS; ++l) {
        const float resf = (float)kRes[l];
        const float fx = px * resf, fy = py * resf, fz = pz * resf;
        const float flx = floorf(fx), fly = floorf(fy), flz = floorf(fz);
        const float wx = fx - flx, wy = fy - fly, wz = fz - flz;
        const float ux = 1.0f - wx, uy = 1.0f - wy, uz = 1.0f - wz;
        const uint32_t hx0 = (uint32_t)(int)flx * P1, hx1 = hx0 + P1;
        const uint32_t hy0 = (uint32_t)(int)fly * P2, hy1 = hy0 + P2;
        const uint32_t hz0 = (uint32_t)(int)flz * P3, hz1 = hz0 + P3;
        const float* __restrict__ tab = tables + (size_t)l * (TABLE_SIZE * FEAT);
        float f0 = 0.0f, f1 = 0.0f;
#pragma unroll
        for (int c = 0; c < 8; ++c) {
            const uint32_t hx = (c & 4) ? hx1 : hx0;
            const uint32_t hy = (c & 2) ? hy1 : hy0;
            const uint32_t hz = (c & 1) ? hz1 : hz0;
            const uint32_t idx = (hx ^ hy ^ hz) & TMASK;
            const float2 v = *reinterpret_cast<const float2*>(tab + (size_t)idx * FEAT);
            const float w = ((c & 4) ? wx : ux) * ((c & 2) ? wy : uy) * ((c & 1) ? wz : uz);
            f0 = fmaf(w, v.x, f0);
            f1 = fmaf(w, v.y, f1);
        }
        outv[2 * l + 0] = f0;
        outv[2 * l + 1] = f1;
    }
    float4* __restrict__ o4 = reinterpret_cast<float4*>(out + (size_t)i * (2 * LEVELS));
#pragma unroll
    for (int k = 0; k < 8; ++k) {
        o4[k] = make_float4(outv[4 * k + 0], outv[4 * k + 1],
                            outv[4 * k + 2], outv[4 * k + 3]);
    }
}

extern "C" void kernel_launch(void* const* d_in, const int* in_sizes, int n_in,
                              void* d_out, int out_size, void* d_ws, size_t ws_size,
                              hipStream_t stream) {
    const float* x = (const float*)d_in[0];
    const float* tables = (const float*)d_in[1];
    float* out = (float*)d_out;
    const int n = in_sizes[0] / 3;

    const size_t ws_elems = (size_t)LEVELS * (size_t)n;          // f32x2 results
    const size_t needA = (ws_elems + NDENSE6 + 2) * sizeof(f32x2);  // dense levels 0-5
    const size_t needB = (ws_elems + NDENSE5 + 2) * sizeof(f32x2);  // dense levels 0-4

    if (ws_size >= needB) {
        const int  planA  = (ws_size >= needA);
        const int  ndlev  = planA ? 6 : 5;
        const int  l0     = planA ? 6 : 5;
        const int  total  = planA ? NDENSE6 : NDENSE5;
        f32x2* ws    = (f32x2*)d_ws;
        f32x2* dense = ws + ws_elems;

        hipLaunchKernelGGL(remap_kernel, dim3((total + 255) / 256), dim3(256), 0, stream,
                           tables, dense, total);

        const int nb512 = (n + 511) / 512;
        hipLaunchKernelGGL(encode_dense_kernel, dim3(nb512), dim3(256), 0, stream,
                           x, dense, ws, n, ndlev);
        hipLaunchKernelGGL(encode_level_kernel, dim3(nb512 * (LEVELS - l0)), dim3(256), 0, stream,
                           x, tables, ws, n, nb512, l0);

        const int nb256 = (n + 255) / 256;
        hipLaunchKernelGGL(transpose_kernel, dim3(nb256), dim3(256), 0, stream,
                           ws, out, n);
    } else {
        const int nb = (n + 255) / 256;
        hipLaunchKernelGGL(hashgrid_enc_kernel, dim3(nb), dim3(256), 0, stream,
                           x, tables, out, n);
    }
}

// Round 3
// 1020.408 us; speedup vs baseline: 1.1032x; 1.0268x over previous
//
#include <hip/hip_runtime.h>
#include <stdint.h>

#define LEVELS 16
#define FEAT 2
#define TABLE_SIZE 524288
#define TMASK (TABLE_SIZE - 1)

typedef float f32x2 __attribute__((ext_vector_type(2)));
typedef float f32x4 __attribute__((ext_vector_type(4)));
typedef float f32x4u __attribute__((ext_vector_type(4), aligned(8)));  // 16B load, 8B-aligned ok

__device__ __constant__ int kRes[LEVELS] = {
    16, 22, 30, 42, 58, 80, 111, 153, 212, 294, 406, 561, 775, 1072, 1481, 2047
};

#define P1 73856093u
#define P2 19349663u
#define P3 83492791u

// Dense (collision-free replicated) tables for levels 0-5 in global scratch.
#define D0 17
#define N0 4913
#define D1 23
#define N1 12167
#define D2 31
#define N2 29791
#define D3 43
#define N3 79507
#define D4 59
#define N4 205379
#define D5 81
#define N5 531441
#define NDENSE5 (N0 + N1 + N2 + N3 + N4)              // plan B: levels 0-4 dense
#define NDENSE6 (NDENSE5 + N5)                        // plan A: levels 0-5 dense

// compile-time tables (folded to immediates in unrolled loops)
constexpr int   cDD[6]   = { D0, D1, D2, D3, D4, D5 };
constexpr int   cDOff[6] = { 0, N0, N0+N1, N0+N1+N2, N0+N1+N2+N3, NDENSE5 };
constexpr float cDRes[6] = { 16.0f, 22.0f, 30.0f, 42.0f, 58.0f, 80.0f };
constexpr int   cDCum[7] = { 0, N0, N0+N1, N0+N1+N2, N0+N1+N2+N3, NDENSE5, NDENSE6 };

// ---------------- one-time remap: hashed tables -> dense [D^3] layout ----------------
__global__ __launch_bounds__(256) void remap_kernel(
    const float* __restrict__ tables,
    f32x2* __restrict__ dense,
    int total)   // NDENSE5 or NDENSE6
{
    const int d = blockIdx.x * 256 + threadIdx.x;
    if (d >= total) return;
    int l = 0;
#pragma unroll
    for (int k = 1; k < 6; ++k)
        if (d >= cDCum[k]) l = k;
    const int D   = cDD[l];
    const int rel = d - cDCum[l];
    const uint32_t bx = rel / (D * D);
    const uint32_t r  = rel - bx * (D * D);
    const uint32_t by = r / D;
    const uint32_t bz = r - by * D;
    const uint32_t slot = ((bx * P1) ^ (by * P2) ^ (bz * P3)) & TMASK;
    const f32x2* __restrict__ tab = reinterpret_cast<const f32x2*>(tables) + (size_t)l * TABLE_SIZE;
    dense[d] = tab[slot];
}

// ---------------- hashed levels l0..15: proven structure (2 pts/thread, 75us/level) ----------------
__global__ __launch_bounds__(256) void encode_level_kernel(
    const float* __restrict__ x,
    const float* __restrict__ tables,
    f32x2* __restrict__ ws,
    int n, int nb, int l0)
{
    const int l   = l0 + blockIdx.x / nb;
    const int blk = blockIdx.x - (l - l0) * nb;
    const int t   = threadIdx.x;
    const int p0  = blk * 512;

    __shared__ float sx[512 * 3];
    const long long total3 = (long long)n * 3;
    const long long gbase  = (long long)p0 * 3;
#pragma unroll
    for (int k = 0; k < 6; ++k) {
        long long g = gbase + k * 256 + t;
        sx[k * 256 + t] = (g < total3) ? __builtin_nontemporal_load(x + g) : 0.0f;
    }
    __syncthreads();

    const float resf = (float)kRes[l];
    const f32x2* __restrict__ tab = reinterpret_cast<const f32x2*>(tables) + (size_t)l * TABLE_SIZE;

    uint32_t idx[2][8];
    float    wgt[2][8];
#pragma unroll
    for (int s = 0; s < 2; ++s) {
        const int tp = s * 256 + t;
        const float fx = sx[3 * tp + 0] * resf;
        const float fy = sx[3 * tp + 1] * resf;
        const float fz = sx[3 * tp + 2] * resf;
        const float flx = floorf(fx), fly = floorf(fy), flz = floorf(fz);
        const float wx = fx - flx, wy = fy - fly, wz = fz - flz;
        const float ux = 1.0f - wx, uy = 1.0f - wy, uz = 1.0f - wz;
        const uint32_t hx0 = (uint32_t)(int)flx * P1, hx1 = hx0 + P1;
        const uint32_t hy0 = (uint32_t)(int)fly * P2, hy1 = hy0 + P2;
        const uint32_t hz0 = (uint32_t)(int)flz * P3, hz1 = hz0 + P3;
#pragma unroll
        for (int c = 0; c < 8; ++c) {
            const uint32_t hx = (c & 4) ? hx1 : hx0;
            const uint32_t hy = (c & 2) ? hy1 : hy0;
            const uint32_t hz = (c & 1) ? hz1 : hz0;
            idx[s][c] = (hx ^ hy ^ hz) & TMASK;
            wgt[s][c] = ((c & 4) ? wx : ux) * ((c & 2) ? wy : uy) * ((c & 1) ? wz : uz);
        }
    }

    f32x2 v[2][8];
#pragma unroll
    for (int s = 0; s < 2; ++s)
#pragma unroll
        for (int c = 0; c < 8; ++c)
            v[s][c] = tab[idx[s][c]];

#pragma unroll
    for (int s = 0; s < 2; ++s) {
        float f0 = 0.0f, f1 = 0.0f;
#pragma unroll
        for (int c = 0; c < 8; ++c) {
            f0 = fmaf(wgt[s][c], v[s][c].x, f0);
            f1 = fmaf(wgt[s][c], v[s][c].y, f1);
        }
        const int i = p0 + s * 256 + t;
        if (i < n) {
            f32x2 r; r.x = f0; r.y = f1;
            __builtin_nontemporal_store(r, ws + (size_t)l * n + i);
        }
    }
}

// ---------------- finalize: dense levels 0..NDLEV-1 inline + hashed ws + coalesced out ----------------
template<int NDLEV>
__global__ __launch_bounds__(256) void finalize_kernel(
    const float* __restrict__ x,
    const f32x2* __restrict__ dense,
    const f32x2* __restrict__ ws,
    float* __restrict__ out,
    int n)
{
    __shared__ float s[256 * 33];
    __shared__ float sx[256 * 3];
    const int t  = threadIdx.x;
    const int p0 = blockIdx.x * 256;
    const int m  = min(256, n - p0);

    const long long total3 = (long long)n * 3;
    const long long gbase  = (long long)p0 * 3;
#pragma unroll
    for (int k = 0; k < 3; ++k) {
        long long g = gbase + k * 256 + t;
        sx[k * 256 + t] = (g < total3) ? __builtin_nontemporal_load(x + g) : 0.0f;
    }
    __syncthreads();

    if (t < m) {
        const int i = p0 + t;
        constexpr int NH = LEVELS - NDLEV;

        // hashed results: coalesced 8B loads, issued early so they fly under the dense gathers
        f32x2 h[NH];
#pragma unroll
        for (int j = 0; j < NH; ++j)
            h[j] = __builtin_nontemporal_load(ws + (size_t)(NDLEV + j) * n + i);

        const float px = sx[3 * t + 0];
        const float py = sx[3 * t + 1];
        const float pz = sx[3 * t + 2];

#pragma unroll
        for (int l = 0; l < NDLEV; ++l) {
            const int   D    = cDD[l];
            const int   DD   = D * D;
            const float resf = cDRes[l];
            const f32x2* __restrict__ tabd = dense + cDOff[l];
            const float fx = px * resf, fy = py * resf, fz = pz * resf;
            const float flx = floorf(fx), fly = floorf(fy), flz = floorf(fz);
            const float wx = fx - flx, wy = fy - fly, wz = fz - flz;
            const float ux = 1.0f - wx, uy = 1.0f - wy, uz = 1.0f - wz;
            const int base = ((int)flx * D + (int)fly) * D + (int)flz;

            f32x4u v[4];
#pragma unroll
            for (int p = 0; p < 4; ++p) {
                const int off = ((p & 2) ? DD : 0) + ((p & 1) ? D : 0);
                v[p] = *reinterpret_cast<const f32x4u*>(tabd + base + off);
            }
            float f0 = 0.0f, f1 = 0.0f;
#pragma unroll
            for (int p = 0; p < 4; ++p) {
                const float wxy = ((p & 2) ? wx : ux) * ((p & 1) ? wy : uy);
                f0 = fmaf(wxy, fmaf(uz, v[p].x, wz * v[p].z), f0);
                f1 = fmaf(wxy, fmaf(uz, v[p].y, wz * v[p].w), f1);
            }
            s[t * 33 + 2 * l + 0] = f0;
            s[t * 33 + 2 * l + 1] = f1;
        }
#pragma unroll
        for (int j = 0; j < NH; ++j) {
            s[t * 33 + 2 * (NDLEV + j) + 0] = h[j].x;
            s[t * 33 + 2 * (NDLEV + j) + 1] = h[j].y;
        }
    }
    __syncthreads();

    const int nchunk = m * 8;
    f32x4* __restrict__ o4 = reinterpret_cast<f32x4*>(out) + (size_t)p0 * 8;
#pragma unroll
    for (int j = 0; j < 8; ++j) {
        const int cl = j * 256 + t;
        if (cl < nchunk) {
            const int p = cl >> 3, ch = cl & 7;
            f32x4 q;
            q.x = s[p * 33 + ch * 4 + 0];
            q.y = s[p * 33 + ch * 4 + 1];
            q.z = s[p * 33 + ch * 4 + 2];
            q.w = s[p * 33 + ch * 4 + 3];
            __builtin_nontemporal_store(q, o4 + cl);
        }
    }
}

// ---------------- fallback: fused single-kernel path (if ws too small) ----------------
__global__ __launch_bounds__(256) void hashgrid_enc_kernel(
    const float* __restrict__ x,
    const float* __restrict__ tables,
    float* __restrict__ out,
    int n)
{
    __shared__ float sx[256 * 3];
    const int t = threadIdx.x;
    const int block0 = blockIdx.x * 256;
    const long long total3 = (long long)n * 3;
    const long long gbase = (long long)block0 * 3;
#pragma unroll
    for (int k = 0; k < 3; ++k) {
        long long g = gbase + k * 256 + t;
        sx[k * 256 + t] = (g < total3) ? x[g] : 0.0f;
    }
    __syncthreads();
    const int i = block0 + t;
    if (i >= n) return;
    const float px = sx[3 * t + 0];
    const float py = sx[3 * t + 1];
    const float pz = sx[3 * t + 2];
    float outv[2 * LEVELS];
#pragma unroll
    for (int l = 0; l < LEVELS; ++l) {
        const float resf = (float)kRes[l];
        const float fx = px * resf, fy = py * resf, fz = pz * resf;
        const float flx = floorf(fx), fly = floorf(fy), flz = floorf(fz);
        const float wx = fx - flx, wy = fy - fly, wz = fz - flz;
        const float ux = 1.0f - wx, uy = 1.0f - wy, uz = 1.0f - wz;
        const uint32_t hx0 = (uint32_t)(int)flx * P1, hx1 = hx0 + P1;
        const uint32_t hy0 = (uint32_t)(int)fly * P2, hy1 = hy0 + P2;
        const uint32_t hz0 = (uint32_t)(int)flz * P3, hz1 = hz0 + P3;
        const float* __restrict__ tab = tables + (size_t)l * (TABLE_SIZE * FEAT);
        float f0 = 0.0f, f1 = 0.0f;
#pragma unroll
        for (int c = 0; c < 8; ++c) {
            const uint32_t hx = (c & 4) ? hx1 : hx0;
            const uint32_t hy = (c & 2) ? hy1 : hy0;
            const uint32_t hz = (c & 1) ? hz1 : hz0;
            const uint32_t idx = (hx ^ hy ^ hz) & TMASK;
            const float2 v = *reinterpret_cast<const float2*>(tab + (size_t)idx * FEAT);
            const float w = ((c & 4) ? wx : ux) * ((c & 2) ? wy : uy) * ((c & 1) ? wz : uz);
            f0 = fmaf(w, v.x, f0);
            f1 = fmaf(w, v.y, f1);
        }
        outv[2 * l + 0] = f0;
        outv[2 * l + 1] = f1;
    }
    float4* __restrict__ o4 = reinterpret_cast<float4*>(out + (size_t)i * (2 * LEVELS));
#pragma unroll
    for (int k = 0; k < 8; ++k) {
        o4[k] = make_float4(outv[4 * k + 0], outv[4 * k + 1],
                            outv[4 * k + 2], outv[4 * k + 3]);
    }
}

extern "C" void kernel_launch(void* const* d_in, const int* in_sizes, int n_in,
                              void* d_out, int out_size, void* d_ws, size_t ws_size,
                              hipStream_t stream) {
    const float* x = (const float*)d_in[0];
    const float* tables = (const float*)d_in[1];
    float* out = (float*)d_out;
    const int n = in_sizes[0] / 3;

    const size_t ws_elems = (size_t)LEVELS * (size_t)n;          // f32x2 results
    const size_t needA = (ws_elems + NDENSE6 + 2) * sizeof(f32x2);  // dense levels 0-5
    const size_t needB = (ws_elems + NDENSE5 + 2) * sizeof(f32x2);  // dense levels 0-4

    if (ws_size >= needB) {
        const int planA = (ws_size >= needA);
        const int l0    = planA ? 6 : 5;
        const int total = planA ? NDENSE6 : NDENSE5;
        f32x2* ws    = (f32x2*)d_ws;
        f32x2* dense = ws + ws_elems;

        hipLaunchKernelGGL(remap_kernel, dim3((total + 255) / 256), dim3(256), 0, stream,
                           tables, dense, total);

        const int nb512 = (n + 511) / 512;
        hipLaunchKernelGGL(encode_level_kernel, dim3(nb512 * (LEVELS - l0)), dim3(256), 0, stream,
                           x, tables, ws, n, nb512, l0);

        const int nb256 = (n + 255) / 256;
        if (planA) {
            hipLaunchKernelGGL((finalize_kernel<6>), dim3(nb256), dim3(256), 0, stream,
                               x, dense, ws, out, n);
        } else {
            hipLaunchKernelGGL((finalize_kernel<5>), dim3(nb256), dim3(256), 0, stream,
                               x, dense, ws, out, n);
        }
    } else {
        const int nb = (n + 255) / 256;
        hipLaunchKernelGGL(hashgrid_enc_kernel, dim3(nb), dim3(256), 0, stream,
                           x, tables, out, n);
    }
}

// Round 4
// 978.316 us; speedup vs baseline: 1.1507x; 1.0430x over previous
//
#include <hip/hip_runtime.h>
#include <hip/hip_fp16.h>
#include <stdint.h>

#define LEVELS 16
#define FEAT 2
#define TABLE_SIZE 524288
#define TMASK (TABLE_SIZE - 1)

typedef float f32x2 __attribute__((ext_vector_type(2)));
typedef float f32x4 __attribute__((ext_vector_type(4)));
typedef float f32x4u __attribute__((ext_vector_type(4), aligned(8)));  // 16B load, 8B-aligned ok

__device__ __constant__ int kRes[LEVELS] = {
    16, 22, 30, 42, 58, 80, 111, 153, 212, 294, 406, 561, 775, 1072, 1481, 2047
};

#define P1 73856093u
#define P2 19349663u
#define P3 83492791u

// Dense quad-packed (fp16) tables for levels 0..6. D = res+1.
#define NQLEV 7
#define HASH0 7
#define NHASH (LEVELS - HASH0)          // 9 hashed levels

constexpr int   cQD[NQLEV]     = { 17, 23, 31, 43, 59, 81, 112 };
constexpr float cQRes[NQLEV]   = { 16.0f, 22.0f, 30.0f, 42.0f, 58.0f, 80.0f, 111.0f };
constexpr int   cQCum[NQLEV+1] = { 0, 4913, 17080, 46871, 126378, 331757, 863198, 2268126 };
#define NCELLS 2268126                   // total cells across levels 0..6 (stage-1 f32)

// ---------------- remap stage 1: hashed tables -> dense f32 [D^3] cells ----------------
__global__ __launch_bounds__(256) void remap1_kernel(
    const float* __restrict__ tables,
    f32x2* __restrict__ dense)           // [NCELLS]
{
    const int d = blockIdx.x * 256 + threadIdx.x;
    if (d >= NCELLS) return;
    int l = 0;
#pragma unroll
    for (int k = 1; k < NQLEV; ++k)
        if (d >= cQCum[k]) l = k;
    const int D   = cQD[l];
    const int rel = d - cQCum[l];
    const uint32_t bx = rel / (D * D);
    const uint32_t r  = rel - bx * (D * D);
    const uint32_t by = r / D;
    const uint32_t bz = r - by * D;
    const uint32_t slot = ((bx * P1) ^ (by * P2) ^ (bz * P3)) & TMASK;
    const f32x2* __restrict__ tab = reinterpret_cast<const f32x2*>(tables) + (size_t)l * TABLE_SIZE;
    dense[d] = tab[slot];
}

// ---------------- remap stage 2: f32 cells -> fp16 2x2 (y,z) quads, 16B each ----------------
// quad[d] = {c(x,y,z), c(x,y,z+1), c(x,y+1,z), c(x,y+1,z+1)} as 4x half2.
// Quads at y==D-1 / z==D-1 are never read by finalize (base coords <= D-2); we allow a
// small in-buffer overread of the stage-1 region for them (values unused).
__global__ __launch_bounds__(256) void remap2_kernel(
    const f32x2* __restrict__ dense,
    uint4* __restrict__ qtab)            // [NCELLS]
{
    const int d = blockIdx.x * 256 + threadIdx.x;
    if (d >= NCELLS) return;
    int l = 0;
#pragma unroll
    for (int k = 1; k < NQLEV; ++k)
        if (d >= cQCum[k]) l = k;
    const int D   = cQD[l];
    const int rel = d - cQCum[l];

    // rows y and y+1, cells (z, z+1) each: two 16B loads (spatially local -> coalesce/L1-hit)
    const f32x2* __restrict__ dl = dense + cQCum[l];
    const f32x4u a = *reinterpret_cast<const f32x4u*>(dl + rel);          // (y ,z),(y ,z+1)
    const f32x4u b = *reinterpret_cast<const f32x4u*>(dl + rel + D);      // (y+1,z),(y+1,z+1)

    union { __half2 h; uint32_t u; } p0, p1, p2, p3;
    p0.h = __float22half2_rn(make_float2(a.x, a.y));
    p1.h = __float22half2_rn(make_float2(a.z, a.w));
    p2.h = __float22half2_rn(make_float2(b.x, b.y));
    p3.h = __float22half2_rn(make_float2(b.z, b.w));
    qtab[d] = make_uint4(p0.u, p1.u, p2.u, p3.u);
}

// ---------------- hashed levels l0..15: proven structure (2 pts/thread, 75us/level) ----------------
__global__ __launch_bounds__(256) void encode_level_kernel(
    const float* __restrict__ x,
    const float* __restrict__ tables,
    f32x2* __restrict__ ws,              // staging: level l stored at ws + (l-l0)*n
    int n, int nb, int l0)
{
    const int l   = l0 + blockIdx.x / nb;
    const int blk = blockIdx.x - (l - l0) * nb;
    const int t   = threadIdx.x;
    const int p0  = blk * 512;

    __shared__ float sx[512 * 3];
    const long long total3 = (long long)n * 3;
    const long long gbase  = (long long)p0 * 3;
#pragma unroll
    for (int k = 0; k < 6; ++k) {
        long long g = gbase + k * 256 + t;
        sx[k * 256 + t] = (g < total3) ? __builtin_nontemporal_load(x + g) : 0.0f;
    }
    __syncthreads();

    const float resf = (float)kRes[l];
    const f32x2* __restrict__ tab = reinterpret_cast<const f32x2*>(tables) + (size_t)l * TABLE_SIZE;

    uint32_t idx[2][8];
    float    wgt[2][8];
#pragma unroll
    for (int s = 0; s < 2; ++s) {
        const int tp = s * 256 + t;
        const float fx = sx[3 * tp + 0] * resf;
        const float fy = sx[3 * tp + 1] * resf;
        const float fz = sx[3 * tp + 2] * resf;
        const float flx = floorf(fx), fly = floorf(fy), flz = floorf(fz);
        const float wx = fx - flx, wy = fy - fly, wz = fz - flz;
        const float ux = 1.0f - wx, uy = 1.0f - wy, uz = 1.0f - wz;
        const uint32_t hx0 = (uint32_t)(int)flx * P1, hx1 = hx0 + P1;
        const uint32_t hy0 = (uint32_t)(int)fly * P2, hy1 = hy0 + P2;
        const uint32_t hz0 = (uint32_t)(int)flz * P3, hz1 = hz0 + P3;
#pragma unroll
        for (int c = 0; c < 8; ++c) {
            const uint32_t hx = (c & 4) ? hx1 : hx0;
            const uint32_t hy = (c & 2) ? hy1 : hy0;
            const uint32_t hz = (c & 1) ? hz1 : hz0;
            idx[s][c] = (hx ^ hy ^ hz) & TMASK;
            wgt[s][c] = ((c & 4) ? wx : ux) * ((c & 2) ? wy : uy) * ((c & 1) ? wz : uz);
        }
    }

    f32x2 v[2][8];
#pragma unroll
    for (int s = 0; s < 2; ++s)
#pragma unroll
        for (int c = 0; c < 8; ++c)
            v[s][c] = tab[idx[s][c]];

#pragma unroll
    for (int s = 0; s < 2; ++s) {
        float f0 = 0.0f, f1 = 0.0f;
#pragma unroll
        for (int c = 0; c < 8; ++c) {
            f0 = fmaf(wgt[s][c], v[s][c].x, f0);
            f1 = fmaf(wgt[s][c], v[s][c].y, f1);
        }
        const int i = p0 + s * 256 + t;
        if (i < n) {
            f32x2 r; r.x = f0; r.y = f1;
            __builtin_nontemporal_store(r, ws + (size_t)(l - l0) * n + i);
        }
    }
}

// ---------------- finalize: 7 fp16-quad dense levels (2 req/pt/level) + hashed ws + out ----------------
__global__ __launch_bounds__(256) void finalize_kernel(
    const float* __restrict__ x,
    const uint4* __restrict__ qtab,
    const f32x2* __restrict__ ws,        // hashed staging, level 7+j at ws + j*n
    float* __restrict__ out,
    int n)
{
    __shared__ float s[256 * 33];
    __shared__ float sx[256 * 3];
    const int t  = threadIdx.x;
    const int p0 = blockIdx.x * 256;
    const int m  = min(256, n - p0);

    const long long total3 = (long long)n * 3;
    const long long gbase  = (long long)p0 * 3;
#pragma unroll
    for (int k = 0; k < 3; ++k) {
        long long g = gbase + k * 256 + t;
        sx[k * 256 + t] = (g < total3) ? __builtin_nontemporal_load(x + g) : 0.0f;
    }
    __syncthreads();

    if (t < m) {
        const int i = p0 + t;

        // hashed results: coalesced 8B loads, issued early
        f32x2 h[NHASH];
#pragma unroll
        for (int j = 0; j < NHASH; ++j)
            h[j] = __builtin_nontemporal_load(ws + (size_t)j * n + i);

        const float px = sx[3 * t + 0];
        const float py = sx[3 * t + 1];
        const float pz = sx[3 * t + 2];

#pragma unroll
        for (int l = 0; l < NQLEV; ++l) {
            const int   D    = cQD[l];
            const int   DD   = D * D;
            const float resf = cQRes[l];
            const uint4* __restrict__ qt = qtab + cQCum[l];

            const float fx = px * resf, fy = py * resf, fz = pz * resf;
            const float flx = floorf(fx), fly = floorf(fy), flz = floorf(fz);
            const float wx = fx - flx, wy = fy - fly, wz = fz - flz;
            const float ux = 1.0f - wx, uy = 1.0f - wy, uz = 1.0f - wz;
            const int q0 = (((int)flx * D + (int)fly) * D + (int)flz);

            const uint4 A = qt[q0];        // x = bx  : (y,z),(y,z+1),(y+1,z),(y+1,z+1)
            const uint4 B = qt[q0 + DD];   // x = bx+1

            union { uint32_t u; __half2 hh; } c;
            float2 a00, a01, a10, a11, b00, b01, b10, b11;
            c.u = A.x; a00 = __half22float2(c.hh);
            c.u = A.y; a01 = __half22float2(c.hh);
            c.u = A.z; a10 = __half22float2(c.hh);
            c.u = A.w; a11 = __half22float2(c.hh);
            c.u = B.x; b00 = __half22float2(c.hh);
            c.u = B.y; b01 = __half22float2(c.hh);
            c.u = B.z; b10 = __half22float2(c.hh);
            c.u = B.w; b11 = __half22float2(c.hh);

            // f = ux*[uy*(uz*a00+wz*a01) + wy*(uz*a10+wz*a11)] + wx*[...B...]
            const float ya0 = fmaf(uz, a00.x, wz * a01.x), ya1 = fmaf(uz, a10.x, wz * a11.x);
            const float yb0 = fmaf(uz, b00.x, wz * b01.x), yb1 = fmaf(uz, b10.x, wz * b11.x);
            const float f0  = fmaf(ux, fmaf(uy, ya0, wy * ya1), wx * fmaf(uy, yb0, wy * yb1));
            const float za0 = fmaf(uz, a00.y, wz * a01.y), za1 = fmaf(uz, a10.y, wz * a11.y);
            const float zb0 = fmaf(uz, b00.y, wz * b01.y), zb1 = fmaf(uz, b10.y, wz * b11.y);
            const float f1  = fmaf(ux, fmaf(uy, za0, wy * za1), wx * fmaf(uy, zb0, wy * zb1));

            s[t * 33 + 2 * l + 0] = f0;
            s[t * 33 + 2 * l + 1] = f1;
        }
#pragma unroll
        for (int j = 0; j < NHASH; ++j) {
            s[t * 33 + 2 * (NQLEV + j) + 0] = h[j].x;
            s[t * 33 + 2 * (NQLEV + j) + 1] = h[j].y;
        }
    }
    __syncthreads();

    const int nchunk = m * 8;
    f32x4* __restrict__ o4 = reinterpret_cast<f32x4*>(out) + (size_t)p0 * 8;
#pragma unroll
    for (int j = 0; j < 8; ++j) {
        const int cl = j * 256 + t;
        if (cl < nchunk) {
            const int p = cl >> 3, ch = cl & 7;
            f32x4 q;
            q.x = s[p * 33 + ch * 4 + 0];
            q.y = s[p * 33 + ch * 4 + 1];
            q.z = s[p * 33 + ch * 4 + 2];
            q.w = s[p * 33 + ch * 4 + 3];
            __builtin_nontemporal_store(q, o4 + cl);
        }
    }
}

// ---------------- fallback: fused single-kernel path (if ws too small) ----------------
__global__ __launch_bounds__(256) void hashgrid_enc_kernel(
    const float* __restrict__ x,
    const float* __restrict__ tables,
    float* __restrict__ out,
    int n)
{
    __shared__ float sx[256 * 3];
    const int t = threadIdx.x;
    const int block0 = blockIdx.x * 256;
    const long long total3 = (long long)n * 3;
    const long long gbase = (long long)block0 * 3;
#pragma unroll
    for (int k = 0; k < 3; ++k) {
        long long g = gbase + k * 256 + t;
        sx[k * 256 + t] = (g < total3) ? x[g] : 0.0f;
    }
    __syncthreads();
    const int i = block0 + t;
    if (i >= n) return;
    const float px = sx[3 * t + 0];
    const float py = sx[3 * t + 1];
    const float pz = sx[3 * t + 2];
    float outv[2 * LEVELS];
#pragma unroll
    for (int l = 0; l < LEVELS; ++l) {
        const float resf = (float)kRes[l];
        const float fx = px * resf, fy = py * resf, fz = pz * resf;
        const float flx = floorf(fx), fly = floorf(fy), flz = floorf(fz);
        const float wx = fx - flx, wy = fy - fly, wz = fz - flz;
        const float ux = 1.0f - wx, uy = 1.0f - wy, uz = 1.0f - wz;
        const uint32_t hx0 = (uint32_t)(int)flx * P1, hx1 = hx0 + P1;
        const uint32_t hy0 = (uint32_t)(int)fly * P2, hy1 = hy0 + P2;
        const uint32_t hz0 = (uint32_t)(int)flz * P3, hz1 = hz0 + P3;
        const float* __restrict__ tab = tables + (size_t)l * (TABLE_SIZE * FEAT);
        float f0 = 0.0f, f1 = 0.0f;
#pragma unroll
        for (int c = 0; c < 8; ++c) {
            const uint32_t hx = (c & 4) ? hx1 : hx0;
            const uint32_t hy = (c & 2) ? hy1 : hy0;
            const uint32_t hz = (c & 1) ? hz1 : hz0;
            const uint32_t idx = (hx ^ hy ^ hz) & TMASK;
            const float2 v = *reinterpret_cast<const float2*>(tab + (size_t)idx * FEAT);
            const float w = ((c & 4) ? wx : ux) * ((c & 2) ? wy : uy) * ((c & 1) ? wz : uz);
            f0 = fmaf(w, v.x, f0);
            f1 = fmaf(w, v.y, f1);
        }
        outv[2 * l + 0] = f0;
        outv[2 * l + 1] = f1;
    }
    float4* __restrict__ o4 = reinterpret_cast<float4*>(out + (size_t)i * (2 * LEVELS));
#pragma unroll
    for (int k = 0; k < 8; ++k) {
        o4[k] = make_float4(outv[4 * k + 0], outv[4 * k + 1],
                            outv[4 * k + 2], outv[4 * k + 3]);
    }
}

extern "C" void kernel_launch(void* const* d_in, const int* in_sizes, int n_in,
                              void* d_out, int out_size, void* d_ws, size_t ws_size,
                              hipStream_t stream) {
    const float* x = (const float*)d_in[0];
    const float* tables = (const float*)d_in[1];
    float* out = (float*)d_out;
    const int n = in_sizes[0] / 3;

    // ws layout: [hashed staging: NHASH*n f32x2][align16][fp16 quads: NCELLS*16B][stage1 f32 cells: NCELLS*8B]
    const size_t stag_b = (size_t)NHASH * (size_t)n * sizeof(f32x2);
    const size_t qoff   = (stag_b + 15) & ~(size_t)15;
    const size_t s1off  = qoff + (size_t)NCELLS * sizeof(uint4);
    const size_t need   = s1off + ((size_t)NCELLS + 2 * 112) * sizeof(f32x2);  // + overread slack

    if (ws_size >= need) {
        f32x2* staging = (f32x2*)d_ws;
        uint4* qtab    = (uint4*)((char*)d_ws + qoff);
        f32x2* stage1  = (f32x2*)((char*)d_ws + s1off);

        const int nbcell = (NCELLS + 255) / 256;
        hipLaunchKernelGGL(remap1_kernel, dim3(nbcell), dim3(256), 0, stream, tables, stage1);
        hipLaunchKernelGGL(remap2_kernel, dim3(nbcell), dim3(256), 0, stream, stage1, qtab);

        const int nb512 = (n + 511) / 512;
        hipLaunchKernelGGL(encode_level_kernel, dim3(nb512 * NHASH), dim3(256), 0, stream,
                           x, tables, staging, n, nb512, HASH0);

        const int nb256 = (n + 255) / 256;
        hipLaunchKernelGGL(finalize_kernel, dim3(nb256), dim3(256), 0, stream,
                           x, qtab, staging, out, n);
    } else {
        const int nb = (n + 255) / 256;
        hipLaunchKernelGGL(hashgrid_enc_kernel, dim3(nb), dim3(256), 0, stream,
                           x, tables, out, n);
    }
}